// Round 2
// baseline (103.953 us; speedup 1.0000x reference)
//
#include <hip/hip_runtime.h>

// SMILESConstraintLayer: out = logits(B,64) + constraint mask(previous_tokens(B,512)).
// One 64-lane wave per row; lane l owns vocab entry l for the output.
//
// Tokens: OPEN_P=0 CLOSE_P=1 OPEN_S=2 CLOSE_S=3 GT=4 PCT=5 EQ=6 HASH=7
//         C=8 O=9 N=10, digits 11..20.

#define TOK_GT   4
#define TOK_PCT  5
#define TOK_EQ   6
#define TOK_HASH 7
#define TOK_C    8
#define TOK_O    9
#define TOK_N    10
#define NEGV     (-1000000000.0f)
#define SEQ      512
#define VOCAB    64

__device__ __forceinline__ int tok_delta(int t) {
    // +1 for OPEN_P(0)/OPEN_S(2), -1 for CLOSE_P(1)/CLOSE_S(3), else 0
    return (t < 4) ? (1 - 2 * (t & 1)) : 0;
}

__device__ __forceinline__ int is_bond(int t) {
    return (t == TOK_EQ) | (t == TOK_HASH);
}

__global__ __launch_bounds__(256) void smiles_constraint_kernel(
    const float* __restrict__ logits,
    const int*   __restrict__ tokens,
    float*       __restrict__ out,
    int B)
{
    const int wave = (int)((blockIdx.x * blockDim.x + threadIdx.x) >> 6);
    const int lane = (int)(threadIdx.x & 63);
    if (wave >= B) return;

    const long long rowbase = (long long)wave * SEQ;
    const int4* tp = reinterpret_cast<const int4*>(tokens + rowbase);

    // Coalesced: seg0 covers tokens[0..255], seg1 covers tokens[256..511].
    const int4 a = tp[lane];        // tokens[lane*4 .. lane*4+3]
    const int4 b = tp[64 + lane];   // tokens[256+lane*4 .. +3]

    // ---- balance: cumsum of +-1 deltas; need total and min inclusive prefix ----
    // per-lane local prefix (segment 0)
    int d0 = tok_delta(a.x), d1 = tok_delta(a.y), d2 = tok_delta(a.z), d3 = tok_delta(a.w);
    int p1 = d0, p2 = p1 + d1, p3 = p2 + d2, p4 = p3 + d3;
    const int s0 = p4;                              // lane's delta-sum, seg0, in [-4,4]
    const int m0 = min(min(p1, p2), min(p3, p4));   // lane's min local prefix, seg0
    // per-lane local prefix (segment 1)
    d0 = tok_delta(b.x); d1 = tok_delta(b.y); d2 = tok_delta(b.z); d3 = tok_delta(b.w);
    p1 = d0; p2 = p1 + d1; p3 = p2 + d2; p4 = p3 + d3;
    const int s1 = p4;
    const int m1 = min(min(p1, p2), min(p3, p4));

    // Packed dual inclusive sum-scan across 64 lanes.
    // Field element = s + 4 in [0,8]; inclusive sums <= 64*8 = 512 < 2^16,
    // so low field never carries into high field.
    int packed = ((s1 + 4) << 16) | (s0 + 4);
    #pragma unroll
    for (int off = 1; off < 64; off <<= 1) {
        const int o = __shfl_up(packed, off);
        if (lane >= off) packed += o;
    }
    const int bias = 4 * (lane + 1);
    const int inc0 = (packed & 0xFFFF) - bias;      // inclusive prefix sum, seg0
    const int inc1 = (packed >> 16)    - bias;      // inclusive prefix sum, seg1

    const int totp = __shfl(packed, 63);
    const int tot0 = (totp & 0xFFFF) - 256;         // 4*64
    const int tot1 = (totp >> 16)    - 256;
    const int tot  = tot0 + tot1;

    // min inclusive prefix over all 512 positions:
    // candidate = exclusive prefix + local min prefix, seg1 offset by tot0
    int cand = min((inc0 - s0) + m0, tot0 + (inc1 - s1) + m1);
    #pragma unroll
    for (int off = 1; off < 64; off <<= 1) {
        cand = min(cand, __shfl_xor(cand, off));
    }
    const int depth_end = tot - min(cand, 0);
    const bool unbalanced = depth_end > 0;

    // ---- last token + valence tail (tokens 509,510,511 live in lane 63's b) ----
    const int last = __shfl(b.w, 63);   // tokens[511]
    const int t509 = __shfl(b.y, 63);
    const int t510 = __shfl(b.z, 63);
    const int bond = is_bond(t509) + is_bond(t510) + is_bond(last);
    const int mb = (last == TOK_C) ? 4 : (last == TOK_O) ? 2 : (last == TOK_N) ? 3 : 99;
    const bool val_cond = bond >= mb;

    // ---- ring closure: any i in [0,510]: tokens[i]==last && tokens[i+1]==PCT ----
    int nexta = __shfl_down(a.x, 1);          // next lane's first seg0 token
    const int firstb = __shfl(b.x, 0);        // tokens[256]
    if (lane == 63) nexta = firstb;           // pair (255,256)
    int nextb = __shfl_down(b.x, 1);
    if (lane == 63) nextb = -1;               // pair (511,512) doesn't exist

    const bool hit =
        (a.x == last && a.y == TOK_PCT) || (a.y == last && a.z == TOK_PCT) ||
        (a.z == last && a.w == TOK_PCT) || (a.w == last && nexta == TOK_PCT) ||
        (b.x == last && b.y == TOK_PCT) || (b.y == last && b.z == TOK_PCT) ||
        (b.z == last && b.w == TOK_PCT) || (b.w == last && nextb == TOK_PCT);
    const bool ring_hit = __any(hit) != 0;
    const bool is_digit = (last >= 11) && (last <= 20);
    const bool ring_cond = is_digit && ring_hit;

    // ---- write output: lane l owns vocab entry l ----
    const bool masked =
        ((lane == TOK_GT) && unbalanced) ||
        ((lane == last)   && ring_cond)  ||
        (((lane == TOK_EQ) || (lane == TOK_HASH)) && val_cond);

    const long long o = (long long)wave * VOCAB + lane;
    out[o] = logits[o] + (masked ? NEGV : 0.0f);
}

extern "C" void kernel_launch(void* const* d_in, const int* in_sizes, int n_in,
                              void* d_out, int out_size, void* d_ws, size_t ws_size,
                              hipStream_t stream) {
    const float* logits = (const float*)d_in[0];
    const int*   tokens = (const int*)d_in[1];
    // d_in[2] = current_step (unused by the math)
    float* out = (float*)d_out;

    const int B = in_sizes[0] / VOCAB;          // 32768
    const int waves_per_block = 256 / 64;       // 4 rows per block
    const int grid = (B + waves_per_block - 1) / waves_per_block;

    smiles_constraint_kernel<<<grid, 256, 0, stream>>>(logits, tokens, out, B);
}